// Round 1
// baseline (561.984 us; speedup 1.0000x reference)
//
#include <hip/hip_runtime.h>

#define NGROUPS 32
#define BATCH   8
#define CHANNELS 64
#define GN_EPS 1e-5f

// ws layout (floats): s1[BATCH*NGROUPS] | s2[BATCH*NGROUPS] | cnt[BATCH]
#define WS_S2   (BATCH * NGROUPS)
#define WS_CNT  (2 * BATCH * NGROUPS)
#define WS_TOT  (2 * BATCH * NGROUPS + BATCH)

__global__ void zero_ws_kernel(float* __restrict__ ws) {
    for (int i = threadIdx.x; i < WS_TOT; i += blockDim.x) ws[i] = 0.0f;
}

__global__ __launch_bounds__(256) void stats_kernel(
    const float4* __restrict__ f4, const int* __restrict__ bidx,
    float* __restrict__ ws, int n_f4)
{
    float s1[BATCH][2], s2[BATCH][2], cnt[BATCH];
#pragma unroll
    for (int b = 0; b < BATCH; ++b) {
        s1[b][0] = s1[b][1] = s2[b][0] = s2[b][1] = cnt[b] = 0.0f;
    }

    const int stride = gridDim.x * blockDim.x;
    const int j0 = blockIdx.x * blockDim.x + threadIdx.x;

    // stride % 16 == 0, so quad index q = j & 15 is loop-invariant per thread
    int j = j0;
    for (; j + stride < n_f4; j += 2 * stride) {
        float4 v0 = f4[j];
        float4 v1 = f4[j + stride];
        int b0 = bidx[j >> 4];
        int b1 = bidx[(j + stride) >> 4];

        float p00 = v0.x + v0.y, p01 = v0.z + v0.w;
        float q00 = fmaf(v0.x, v0.x, v0.y * v0.y);
        float q01 = fmaf(v0.z, v0.z, v0.w * v0.w);
        float p10 = v1.x + v1.y, p11 = v1.z + v1.w;
        float q10 = fmaf(v1.x, v1.x, v1.y * v1.y);
        float q11 = fmaf(v1.z, v1.z, v1.w * v1.w);
#pragma unroll
        for (int bb = 0; bb < BATCH; ++bb) {
            float m0 = (b0 == bb) ? 1.0f : 0.0f;
            float m1 = (b1 == bb) ? 1.0f : 0.0f;
            s1[bb][0] = fmaf(m0, p00, s1[bb][0]);
            s1[bb][1] = fmaf(m0, p01, s1[bb][1]);
            s2[bb][0] = fmaf(m0, q00, s2[bb][0]);
            s2[bb][1] = fmaf(m0, q01, s2[bb][1]);
            cnt[bb] += m0;
            s1[bb][0] = fmaf(m1, p10, s1[bb][0]);
            s1[bb][1] = fmaf(m1, p11, s1[bb][1]);
            s2[bb][0] = fmaf(m1, q10, s2[bb][0]);
            s2[bb][1] = fmaf(m1, q11, s2[bb][1]);
            cnt[bb] += m1;
        }
    }
    if (j < n_f4) {
        float4 v0 = f4[j];
        int b0 = bidx[j >> 4];
        float p00 = v0.x + v0.y, p01 = v0.z + v0.w;
        float q00 = fmaf(v0.x, v0.x, v0.y * v0.y);
        float q01 = fmaf(v0.z, v0.z, v0.w * v0.w);
#pragma unroll
        for (int bb = 0; bb < BATCH; ++bb) {
            float m0 = (b0 == bb) ? 1.0f : 0.0f;
            s1[bb][0] = fmaf(m0, p00, s1[bb][0]);
            s1[bb][1] = fmaf(m0, p01, s1[bb][1]);
            s2[bb][0] = fmaf(m0, q00, s2[bb][0]);
            s2[bb][1] = fmaf(m0, q01, s2[bb][1]);
            cnt[bb] += m0;
        }
    }

    // Block-level reduction in LDS, then global atomics.
    __shared__ float l_s1[BATCH * NGROUPS];
    __shared__ float l_s2[BATCH * NGROUPS];
    __shared__ float l_cnt[BATCH];
    for (int i = threadIdx.x; i < BATCH * NGROUPS; i += blockDim.x) {
        l_s1[i] = 0.0f; l_s2[i] = 0.0f;
    }
    if (threadIdx.x < BATCH) l_cnt[threadIdx.x] = 0.0f;
    __syncthreads();

    const int q = j0 & 15;          // loop-invariant quad
    const int g0 = 2 * q, g1 = 2 * q + 1;
#pragma unroll
    for (int b = 0; b < BATCH; ++b) {
        atomicAdd(&l_s1[b * NGROUPS + g0], s1[b][0]);
        atomicAdd(&l_s1[b * NGROUPS + g1], s1[b][1]);
        atomicAdd(&l_s2[b * NGROUPS + g0], s2[b][0]);
        atomicAdd(&l_s2[b * NGROUPS + g1], s2[b][1]);
        atomicAdd(&l_cnt[b], cnt[b]);
    }
    __syncthreads();

    for (int i = threadIdx.x; i < BATCH * NGROUPS; i += blockDim.x) {
        atomicAdd(&ws[i], l_s1[i]);
        atomicAdd(&ws[WS_S2 + i], l_s2[i]);
    }
    if (threadIdx.x < BATCH) atomicAdd(&ws[WS_CNT + threadIdx.x], l_cnt[threadIdx.x]);
}

#define LDS_STRIDE 68   // 64 + 4: keeps 16B alignment for [b][4q], breaks bank pattern

__global__ __launch_bounds__(256) void norm_kernel(
    const float4* __restrict__ f4, const int* __restrict__ bidx,
    const float* __restrict__ weight, const float* __restrict__ bias,
    const float* __restrict__ ws, float4* __restrict__ out4, int n_f4)
{
    __shared__ __align__(16) float sc[BATCH][LDS_STRIDE];
    __shared__ __align__(16) float sh[BATCH][LDS_STRIDE];

    for (int t = threadIdx.x; t < BATCH * CHANNELS; t += blockDim.x) {
        int b = t >> 6, c = t & 63, g = c >> 1;
        float s1v = ws[b * NGROUPS + g];
        float s2v = ws[WS_S2 + b * NGROUPS + g];
        float cntf = ws[WS_CNT + b];            // = 16 * Nb
        float denom = fmaxf(cntf * 0.125f, 1.0f); // Nb * Cg
        float mean = s1v / denom;
        float var = s2v / denom - mean * mean;
        float inv = rsqrtf(var + GN_EPS);
        float w = weight[c];
        sc[b][c] = inv * w;
        sh[b][c] = bias[c] - mean * inv * w;
    }
    __syncthreads();

    const int stride = gridDim.x * blockDim.x;
    const int j0 = blockIdx.x * blockDim.x + threadIdx.x;
    const int q4 = (j0 & 15) * 4;   // loop-invariant channel base

    int j = j0;
    for (; j + stride < n_f4; j += 2 * stride) {
        float4 v0 = f4[j];
        float4 v1 = f4[j + stride];
        int b0 = bidx[j >> 4];
        int b1 = bidx[(j + stride) >> 4];
        float4 s0 = *(const float4*)&sc[b0][q4];
        float4 h0 = *(const float4*)&sh[b0][q4];
        float4 s1v = *(const float4*)&sc[b1][q4];
        float4 h1 = *(const float4*)&sh[b1][q4];
        float4 o0, o1;
        o0.x = fmaf(v0.x, s0.x, h0.x);
        o0.y = fmaf(v0.y, s0.y, h0.y);
        o0.z = fmaf(v0.z, s0.z, h0.z);
        o0.w = fmaf(v0.w, s0.w, h0.w);
        o1.x = fmaf(v1.x, s1v.x, h1.x);
        o1.y = fmaf(v1.y, s1v.y, h1.y);
        o1.z = fmaf(v1.z, s1v.z, h1.z);
        o1.w = fmaf(v1.w, s1v.w, h1.w);
        out4[j] = o0;
        out4[j + stride] = o1;
    }
    if (j < n_f4) {
        float4 v0 = f4[j];
        int b0 = bidx[j >> 4];
        float4 s0 = *(const float4*)&sc[b0][q4];
        float4 h0 = *(const float4*)&sh[b0][q4];
        float4 o0;
        o0.x = fmaf(v0.x, s0.x, h0.x);
        o0.y = fmaf(v0.y, s0.y, h0.y);
        o0.z = fmaf(v0.z, s0.z, h0.z);
        o0.w = fmaf(v0.w, s0.w, h0.w);
        out4[j] = o0;
    }
}

extern "C" void kernel_launch(void* const* d_in, const int* in_sizes, int n_in,
                              void* d_out, int out_size, void* d_ws, size_t ws_size,
                              hipStream_t stream) {
    const float* features = (const float*)d_in[0];
    const float* weight   = (const float*)d_in[1];
    const float* bias     = (const float*)d_in[2];
    const int*   bidx     = (const int*)d_in[3];
    float* ws = (float*)d_ws;
    float* out = (float*)d_out;

    const int n_f4 = in_sizes[0] / 4;   // N*C/4 float4s

    zero_ws_kernel<<<1, 256, 0, stream>>>(ws);
    stats_kernel<<<2048, 256, 0, stream>>>((const float4*)features, bidx, ws, n_f4);
    norm_kernel<<<2048, 256, 0, stream>>>((const float4*)features, bidx, weight, bias,
                                          ws, (float4*)out, n_f4);
}